// Round 12
// baseline (154.138 us; speedup 1.0000x reference)
//
#include <hip/hip_runtime.h>
#include <cstdint>
#include <cstddef>

// Problem constants (B=8, C=512, H=W=64, HEAD_DIM=64, PS=2)
#define T_TOK  2048   // k_sel * ps*ps tokens per (b,head)
#define NPATCH 1024
#define KSEL   512
#define BH_N   64     // B * nh

typedef unsigned short u16;
typedef __attribute__((ext_vector_type(8))) short bf16x8;   // MFMA A/B frag (4 VGPR)
typedef __attribute__((ext_vector_type(4))) float f32x4;
typedef __attribute__((ext_vector_type(16))) float f32x16;  // 32x32 MFMA C/D frag

// Workspace layout (bytes). Total = ~80.3 MiB
#define WS_Q   ((size_t)0)            // bf16 Qp[64][64 g32][4 kd][64 lane][8] (frag-major Q, pre-scaled)
#define WS_K   ((size_t)16 << 20)     // bf16 Kp[64][32kt][8frag][64lane][8]  (fragment-major K)
#define WS_VT  ((size_t)32 << 20)     // bf16 Vp[64][32kt][8frag][64lane][8]  (fragment-major V)
#define WS_OT  ((size_t)48 << 20)     // f32  [64][2048][64] out tokens (t-major); first 16MiB double as tok buffer
#define WS_INV ((size_t)80 << 20)     // i32  [64][1024]

// bf16-Schraudolph: pattern(s) = trunc(s*128 + EMAGIC) is the bf16 bits of
// ~exp2(s). 16256 = 127<<7 bias; +0.5 trunc->round; -4.5 minimax correction.
#define EMAGIC 16252.0f

static __device__ __forceinline__ u16 f2bf(float f){
  union { float f; unsigned u; } un; un.f = f;
  return (u16)((un.u + 0x7FFFu + ((un.u >> 16) & 1u)) >> 16);  // RNE
}

static __device__ __forceinline__ float bfbits(unsigned u){
  union { unsigned u; float f; } un; un.u = u; return un.f;
}

static __device__ __forceinline__ void gload16(const void* g, void* l){
  __builtin_amdgcn_global_load_lds(
      (const __attribute__((address_space(1))) void*)g,
      (__attribute__((address_space(3))) void*)l, 16, 0, 0);
}

// ---- inverse patch map: inv[bh][p] = selected index kk, or -1 ------------
__global__ __launch_bounds__(512)
void k_inv(const int* __restrict__ topk, int* __restrict__ inv){
  inv[blockIdx.x*NPATCH + topk[blockIdx.x*KSEL + threadIdx.x]] = threadIdx.x;
}

// ---- token build: dense layout-order read of x, write selected tokens ----
__global__ __launch_bounds__(256)
void k_tok(const float* __restrict__ x, const int* __restrict__ inv,
           u16* __restrict__ tok){
  __shared__ u16 tile[64][132];   // [d][pix]
  __shared__ int invs[32];
  const int tid = threadIdx.x;
  const int pr = blockIdx.x, bh = blockIdx.y;
  const int b = bh >> 3, h = bh & 7;
  if (tid < 32) invs[tid] = inv[bh*NPATCH + pr*32 + tid];
  const float* xb = x + ((size_t)(b*512 + h*64)*64 + 2*pr)*64;
  #pragma unroll
  for (int i = 0; i < 8; ++i){
    const int f = i*1024 + tid*4;
    const int d = f >> 7, y = (f >> 6) & 1, xx = f & 63;
    float4 v = *(const float4*)(xb + ((size_t)d*64 + y)*64 + xx);
    unsigned lo, hi;
    asm("v_cvt_pk_bf16_f32 %0, %1, %2" : "=v"(lo) : "v"(v.x), "v"(v.y));
    asm("v_cvt_pk_bf16_f32 %0, %1, %2" : "=v"(hi) : "v"(v.z), "v"(v.w));
    uint2 pk2; pk2.x = lo; pk2.y = hi;
    *(uint2*)&tile[d][y*64 + xx] = pk2;
  }
  __syncthreads();
  const int p = tid >> 3, j = tid & 7;
  const int kk = invs[p];
  if (kk >= 0){
    u16* dst = tok + ((size_t)bh*T_TOK + kk*4)*64;
    #pragma unroll
    for (int i = 0; i < 4; ++i){
      const int chunk = j*4 + i;
      const int quad = chunk >> 3, d16 = (chunk & 7)*8;
      const int pix = (quad >> 1)*64 + p*2 + (quad & 1);
      union { u16 s[8]; uint4 q; } un;
      #pragma unroll
      for (int k2 = 0; k2 < 8; ++k2) un.s[k2] = tile[d16 + k2][pix];
      *(uint4*)(dst + quad*64 + d16) = un.q;
    }
  }
}

// ---- QKV GEMM: tokens x W -> Qp, Kp, Vp (all frag-major, coalesced) ------
__global__ __launch_bounds__(256)
void k_qkv(const u16* __restrict__ tok, const float* __restrict__ w,
           const float* __restrict__ bias,
           u16* __restrict__ Qp, u16* __restrict__ Kp, u16* __restrict__ Vp){
  __shared__ u16 Wl[192][72];
  __shared__ float biasl[192];
  __shared__ u16 Tq[64][72];   // [q][d]
  __shared__ u16 Tk[64][72];   // [key][d]
  __shared__ u16 Tv[64][72];   // [d][key]  (transposed for b128 frag reads)
  const int tid = threadIdx.x;
  const int chunk = blockIdx.x;
  const int bh = blockIdx.y;
  for (int i2 = tid; i2 < 192*64; i2 += 256) Wl[i2 >> 6][i2 & 63] = f2bf(w[i2]);
  if (tid < 192) biasl[tid] = bias[tid];
  __syncthreads();

  const int lane = tid & 63, wv = tid >> 6;
  const int c = lane & 15, g = lane >> 4;
  const float QSC = 0.18033688f;   // 0.125 * log2(e)
  for (int tile = 0; tile < 4; ++tile){
    const int t0 = chunk*256 + tile*64;
    const int kt2 = t0 >> 6;
    const int trow = t0 + wv*16 + c;
    const u16* tr = tok + ((size_t)bh*T_TOK + trow)*64;
    const bf16x8 a0 = *(const bf16x8*)(tr + 8*g);
    const bf16x8 a1 = *(const bf16x8*)(tr + 32 + 8*g);
    const int lr = wv*16 + 4*g;           // local output row base (0..60)
    #pragma unroll
    for (int nf = 0; nf < 12; ++nf){
      const int e = nf*16 + c;
      const bf16x8 b0 = *(const bf16x8*)&Wl[e][8*g];
      const bf16x8 b1 = *(const bf16x8*)&Wl[e][32 + 8*g];
      f32x4 acc = {0.f, 0.f, 0.f, 0.f};
      acc = __builtin_amdgcn_mfma_f32_16x16x32_bf16(a0, b0, acc, 0, 0, 0);
      acc = __builtin_amdgcn_mfma_f32_16x16x32_bf16(a1, b1, acc, 0, 0, 0);
      const float bb = biasl[e];
      if (e < 64){
        #pragma unroll
        for (int r2 = 0; r2 < 4; ++r2) Tq[lr + r2][e] = f2bf((acc[r2] + bb)*QSC);
      } else if (e < 128){
        #pragma unroll
        for (int r2 = 0; r2 < 4; ++r2) Tk[lr + r2][e - 64] = f2bf(acc[r2] + bb);
      } else {
        // Tv[d][key]: 4 consecutive keys -> one 8B write
        unsigned u01 = (unsigned)f2bf(acc[0] + bb) | ((unsigned)f2bf(acc[1] + bb) << 16);
        unsigned u23 = (unsigned)f2bf(acc[2] + bb) | ((unsigned)f2bf(acc[3] + bb) << 16);
        uint2 pk2; pk2.x = u01; pk2.y = u23;
        *(uint2*)&Tv[e - 128][lr] = pk2;
      }
    }
    __syncthreads();
    // coalesced frag-major stores: thread -> two 16B slots per tensor
    #pragma unroll
    for (int c2 = 0; c2 < 2; ++c2){
      const int s  = tid*2 + c2;        // 0..511
      const int ls = s & 63, f = s >> 6;
      const int r31 = ls & 31, h2 = ls >> 5;
      // Q: f = g2*4 + kd
      {
        const int g2 = f >> 2, kd = f & 3;
        const bf16x8 v = *(const bf16x8*)&Tq[g2*32 + r31][kd*16 + h2*8];
        *(bf16x8*)(Qp + (size_t)bh*131072 + ((size_t)((t0 >> 5) + g2)*4 + kd)*512 + ls*8) = v;
      }
      // K: f = ds*2 + rh
      {
        const int ds = f >> 1, rh = f & 1;
        const bf16x8 v = *(const bf16x8*)&Tk[rh*32 + r31][ds*16 + h2*8];
        *(bf16x8*)(Kp + (((size_t)bh*32 + kt2)*8 + f)*512 + ls*8) = v;
      }
      // V: f = ks*2 + C
      {
        const int ks = f >> 1, C = f & 1;
        const bf16x8 v = *(const bf16x8*)&Tv[C*32 + r31][ks*16 + h2*8];
        *(bf16x8*)(Vp + (((size_t)bh*32 + kt2)*8 + f)*512 + ls*8) = v;
      }
    }
    __syncthreads();
  }
}

// ---- flash attention: 4 waves x 32 q-rows, targeting 4 waves/SIMD --------
// Frag-major K/V DMA'd to LDS (conflict-free reads). P via integer
// bf16-Schraudolph; row-sum from the SAME bf16 patterns (exact cancellation)
// to avoid the accS AGPR block; 16 MFMA/iter.
__global__ __launch_bounds__(256, 4)
void k_attn(const u16* __restrict__ Qp, const u16* __restrict__ Kp,
            const u16* __restrict__ Vp, float* __restrict__ OT){
  __shared__ u16 KVl[2][8192];   // per buf: 8 K frags [64][8] + 8 V frags
  const int tid = threadIdx.x;
  const int bh = blockIdx.x, qt = blockIdx.y;   // bh-major: qt blocks share one XCD's L2
  const int l = tid & 63, w = tid >> 6;
  const int h = l >> 5, c31 = l & 31;
  const int qbase = qt*128 + w*32;

  // Q fragments: frag-major, coalesced 16B/lane
  bf16x8 qf[4];
  {
    const u16* qpb = Qp + (size_t)bh*131072 + ((size_t)(qt*4 + w)*4)*512 + l*8;
    #pragma unroll
    for (int kd = 0; kd < 4; ++kd) qf[kd] = *(const bf16x8*)(qpb + kd*512);
  }

  f32x16 Z;
  #pragma unroll
  for (int r = 0; r < 16; ++r) Z[r] = 0.f;
  f32x16 accO0 = Z, accO1 = Z;
  float ls = 0.f;

  const u16* gKt = Kp + (size_t)bh*131072;   // 32 tiles x 4096 u16
  const u16* gVt = Vp + (size_t)bh*131072;

  // prologue: DMA tile 0 into buffer 0
  {
    u16* ld = &KVl[0][0] + tid*8;
    gload16(gKt + tid*8,        ld);
    gload16(gKt + 2048 + tid*8, ld + 2048);
    gload16(gVt + tid*8,        ld + 4096);
    gload16(gVt + 2048 + tid*8, ld + 6144);
  }
  __syncthreads();

  int cur = 0;
  for (int kt = 0; kt < 32; ++kt){
    if (kt < 31){   // DMA next tile into the other buffer (drained by end barrier)
      const u16* sk = gKt + (kt + 1)*4096 + tid*8;
      const u16* sv = gVt + (kt + 1)*4096 + tid*8;
      u16* ld = &KVl[cur ^ 1][0] + tid*8;
      gload16(sk,        ld);
      gload16(sk + 2048, ld + 2048);
      gload16(sv,        ld + 4096);
      gload16(sv + 2048, ld + 6144);
    }

    const u16* kb = &KVl[cur][l*8];   // frag f at u16 offset f*512
    const u16* vb = kb + 4096;
    float rs = 0.f;

    // ---- QK: s0 chain (keys 0..31), then s1 chain (keys 32..63) ----
    f32x16 s0, s1;
    __builtin_amdgcn_s_setprio(1);
    s0 = __builtin_amdgcn_mfma_f32_32x32x16_bf16(*(const bf16x8*)(kb),        qf[0], Z,  0, 0, 0);
    s0 = __builtin_amdgcn_mfma_f32_32x32x16_bf16(*(const bf16x8*)(kb + 1024), qf[1], s0, 0, 0, 0);
    s0 = __builtin_amdgcn_mfma_f32_32x32x16_bf16(*(const bf16x8*)(kb + 2048), qf[2], s0, 0, 0, 0);
    s0 = __builtin_amdgcn_mfma_f32_32x32x16_bf16(*(const bf16x8*)(kb + 3072), qf[3], s0, 0, 0, 0);
    s1 = __builtin_amdgcn_mfma_f32_32x32x16_bf16(*(const bf16x8*)(kb + 512),  qf[0], Z,  0, 0, 0);
    s1 = __builtin_amdgcn_mfma_f32_32x32x16_bf16(*(const bf16x8*)(kb + 1536), qf[1], s1, 0, 0, 0);
    s1 = __builtin_amdgcn_mfma_f32_32x32x16_bf16(*(const bf16x8*)(kb + 2560), qf[2], s1, 0, 0, 0);
    s1 = __builtin_amdgcn_mfma_f32_32x32x16_bf16(*(const bf16x8*)(kb + 3584), qf[3], s1, 0, 0, 0);
    __builtin_amdgcn_s_setprio(0);

    // ---- SM(s0): Schraudolph patterns -> paf0, paf1; row-sum from patterns
    unsigned pk0[8];
    #pragma unroll
    for (int i = 0; i < 8; ++i){
      const int lo = (int)fmaf(s0[2*i],   128.f, EMAGIC);
      const int hi = (int)fmaf(s0[2*i+1], 128.f, EMAGIC);
      pk0[i] = (unsigned)(lo | (hi << 16));
      rs += bfbits(pk0[i] << 16) + bfbits(pk0[i] & 0xFFFF0000u);
    }
    bf16x8 paf0, paf1;
    {
      unsigned a0 = pk0[0], b0 = pk0[2], a1 = pk0[1], b1 = pk0[3];
      asm("v_permlane32_swap_b32 %0, %1" : "+v"(a0), "+v"(b0));
      asm("v_permlane32_swap_b32 %0, %1" : "+v"(a1), "+v"(b1));
      union { unsigned u[4]; bf16x8 v; } un;
      un.u[0] = a0; un.u[1] = a1; un.u[2] = b0; un.u[3] = b1;
      paf0 = un.v;
      unsigned c0 = pk0[4], d0 = pk0[6], c1 = pk0[5], d1 = pk0[7];
      asm("v_permlane32_swap_b32 %0, %1" : "+v"(c0), "+v"(d0));
      asm("v_permlane32_swap_b32 %0, %1" : "+v"(c1), "+v"(d1));
      union { unsigned u[4]; bf16x8 v; } un2;
      un2.u[0] = c0; un2.u[1] = c1; un2.u[2] = d0; un2.u[3] = d1;
      paf1 = un2.v;
    }

    // ---- PV ks=0,1 ----
    __builtin_amdgcn_s_setprio(1);
    accO0 = __builtin_amdgcn_mfma_f32_32x32x16_bf16(paf0, *(const bf16x8*)(vb),        accO0, 0, 0, 0);
    accO1 = __builtin_amdgcn_mfma_f32_32x32x16_bf16(paf0, *(const bf16x8*)(vb + 512),  accO1, 0, 0, 0);
    accO0 = __builtin_amdgcn_mfma_f32_32x32x16_bf16(paf1, *(const bf16x8*)(vb + 1024), accO0, 0, 0, 0);
    accO1 = __builtin_amdgcn_mfma_f32_32x32x16_bf16(paf1, *(const bf16x8*)(vb + 1536), accO1, 0, 0, 0);
    __builtin_amdgcn_s_setprio(0);

    // ---- SM(s1) ----
    unsigned pk1[8];
    #pragma unroll
    for (int i = 0; i < 8; ++i){
      const int lo = (int)fmaf(s1[2*i],   128.f, EMAGIC);
      const int hi = (int)fmaf(s1[2*i+1], 128.f, EMAGIC);
      pk1[i] = (unsigned)(lo | (hi << 16));
      rs += bfbits(pk1[i] << 16) + bfbits(pk1[i] & 0xFFFF0000u);
    }
    bf16x8 paf2, paf3;
    {
      unsigned a0 = pk1[0], b0 = pk1[2], a1 = pk1[1], b1 = pk1[3];
      asm("v_permlane32_swap_b32 %0, %1" : "+v"(a0), "+v"(b0));
      asm("v_permlane32_swap_b32 %0, %1" : "+v"(a1), "+v"(b1));
      union { unsigned u[4]; bf16x8 v; } un;
      un.u[0] = a0; un.u[1] = a1; un.u[2] = b0; un.u[3] = b1;
      paf2 = un.v;
      unsigned c0 = pk1[4], d0 = pk1[6], c1 = pk1[5], d1 = pk1[7];
      asm("v_permlane32_swap_b32 %0, %1" : "+v"(c0), "+v"(d0));
      asm("v_permlane32_swap_b32 %0, %1" : "+v"(c1), "+v"(d1));
      union { unsigned u[4]; bf16x8 v; } un2;
      un2.u[0] = c0; un2.u[1] = c1; un2.u[2] = d0; un2.u[3] = d1;
      paf3 = un2.v;
    }

    // ---- PV ks=2,3 ----
    __builtin_amdgcn_s_setprio(1);
    accO0 = __builtin_amdgcn_mfma_f32_32x32x16_bf16(paf2, *(const bf16x8*)(vb + 2048), accO0, 0, 0, 0);
    accO1 = __builtin_amdgcn_mfma_f32_32x32x16_bf16(paf2, *(const bf16x8*)(vb + 2560), accO1, 0, 0, 0);
    accO0 = __builtin_amdgcn_mfma_f32_32x32x16_bf16(paf3, *(const bf16x8*)(vb + 3072), accO0, 0, 0, 0);
    accO1 = __builtin_amdgcn_mfma_f32_32x32x16_bf16(paf3, *(const bf16x8*)(vb + 3584), accO1, 0, 0, 0);
    __builtin_amdgcn_s_setprio(0);

    // ---- row-sum tail ----
    rs += __shfl_xor(rs, 32);
    ls += rs;

    __syncthreads();   // drains next-tile DMA + buffer-swap safety
    cur ^= 1;
  }

  // ---- epilogue: normalize (broadcast 1/ls to acc rows), store -----------
  const float rl = 1.0f / ls;
  #pragma unroll
  for (int r = 0; r < 16; ++r){
    const int qr = (r & 3) + 8*(r >> 2) + 4*h;
    const float sa = __uint_as_float(
        (unsigned)__builtin_amdgcn_ds_bpermute(qr << 2, (int)__float_as_uint(rl)));
    float* dst = OT + ((size_t)bh*T_TOK + qbase + qr)*64;
    dst[c31]      = accO0[r]*sa;
    dst[32 + c31] = accO1[r]*sa;
  }
}

// ---- emit: both-sides-coalesced via LDS transpose ------------------------
__global__ __launch_bounds__(256)
void k_emit(const float* __restrict__ OT, const int* __restrict__ inv,
            float* __restrict__ out){
  __shared__ float obuf[128][68];   // [pix = y*64+x][d], pad 4
  __shared__ int invs[32];
  const int tid = threadIdx.x;
  const int pr = blockIdx.x, bh = blockIdx.y;
  const int b = bh >> 3, h = bh & 7;
  if (tid < 32) invs[tid] = inv[bh*NPATCH + pr*32 + tid];
  __syncthreads();
  const int g = tid >> 3, j = tid & 7;
  const int kk = invs[g];
  const float* tbase = OT + ((size_t)bh*T_TOK + 4*kk)*64 + j*8;
  #pragma unroll
  for (int quad = 0; quad < 4; ++quad){
    float4 v0 = {0.f,0.f,0.f,0.f}, v1 = {0.f,0.f,0.f,0.f};
    if (kk >= 0){
      v0 = *(const float4*)(tbase + quad*64);
      v1 = *(const float4*)(tbase + quad*64 + 4);
    }
    const int pix = (quad >> 1)*64 + g*2 + (quad & 1);
    *(float4*)&obuf[pix][j*8]     = v0;
    *(float4*)&obuf[pix][j*8 + 4] = v1;
  }
  __syncthreads();
  float* ob = out + ((size_t)(b*512 + h*64)*64 + 2*pr)*64;
  #pragma unroll
  for (int it = 0; it < 8; ++it){
    const int rid = it*16 + (tid >> 4);      // d*2 + y
    const int d = rid >> 1, y = rid & 1;
    const int x0 = (tid & 15)*4;
    float4 o;
    o.x = obuf[y*64 + x0 + 0][d];
    o.y = obuf[y*64 + x0 + 1][d];
    o.z = obuf[y*64 + x0 + 2][d];
    o.w = obuf[y*64 + x0 + 3][d];
    *(float4*)(ob + ((size_t)d*64 + y)*64 + x0) = o;
  }
}

extern "C" void kernel_launch(void* const* d_in, const int* in_sizes, int n_in,
                              void* d_out, int out_size, void* d_ws, size_t ws_size,
                              hipStream_t stream){
  const float* x    = (const float*)d_in[0];
  const int*   topk = (const int*)  d_in[1];
  const float* w    = (const float*)d_in[2];
  const float* bias = (const float*)d_in[3];
  float* out = (float*)d_out;
  char* ws = (char*)d_ws;

  u16*   Qp  = (u16*)  (ws + WS_Q);
  u16*   Kp  = (u16*)  (ws + WS_K);
  u16*   Vp  = (u16*)  (ws + WS_VT);
  float* OT  = (float*)(ws + WS_OT);
  u16*   tok = (u16*)  (ws + WS_OT);   // aliases OT; dead before k_attn writes
  int*   inv = (int*)  (ws + WS_INV);

  hipMemsetAsync(inv, 0xFF, BH_N*NPATCH*sizeof(int), stream);
  k_inv <<<BH_N, 512, 0, stream>>>(topk, inv);
  k_tok <<<dim3(32, BH_N), 256, 0, stream>>>(x, inv, tok);
  k_qkv <<<dim3(8, BH_N), 256, 0, stream>>>(tok, w, bias, Qp, Kp, Vp);
  k_attn<<<dim3(BH_N, 16), 256, 0, stream>>>(Qp, Kp, Vp, OT);
  k_emit<<<dim3(32, BH_N), 256, 0, stream>>>(OT, inv, out);
}

// Round 13
// 144.900 us; speedup vs baseline: 1.0638x; 1.0638x over previous
//
#include <hip/hip_runtime.h>
#include <cstdint>
#include <cstddef>

// Problem constants (B=8, C=512, H=W=64, HEAD_DIM=64, PS=2)
#define T_TOK  2048   // k_sel * ps*ps tokens per (b,head)
#define NPATCH 1024
#define KSEL   512
#define BH_N   64     // B * nh

typedef unsigned short u16;
typedef __attribute__((ext_vector_type(8))) short bf16x8;   // MFMA A/B frag (4 VGPR)
typedef __attribute__((ext_vector_type(4))) float f32x4;
typedef __attribute__((ext_vector_type(16))) float f32x16;  // 32x32 MFMA C/D frag

// Workspace layout (bytes). Total = ~80.3 MiB
#define WS_Q   ((size_t)0)            // bf16 Qp[64][64 g32][4 kd][64 lane][8] (frag-major Q, pre-scaled)
#define WS_K   ((size_t)16 << 20)     // bf16 Kp[64][32kt][8frag][64lane][8]  (fragment-major K)
#define WS_VT  ((size_t)32 << 20)     // bf16 Vp[64][32kt][8frag][64lane][8]  (fragment-major V)
#define WS_OT  ((size_t)48 << 20)     // f32  [64][2048][64] out tokens (t-major); first 16MiB double as tok buffer
#define WS_INV ((size_t)80 << 20)     // i32  [64][1024]

// bf16-Schraudolph: pattern(s) = trunc(s*128 + EMAGIC) is the bf16 bits of
// ~exp2(s). 16256 = 127<<7 bias; +0.5 trunc->round; -4.5 minimax correction.
#define EMAGIC 16252.0f

static __device__ __forceinline__ u16 f2bf(float f){
  union { float f; unsigned u; } un; un.f = f;
  return (u16)((un.u + 0x7FFFu + ((un.u >> 16) & 1u)) >> 16);  // RNE
}

static __device__ __forceinline__ void gload16(const void* g, void* l){
  __builtin_amdgcn_global_load_lds(
      (const __attribute__((address_space(1))) void*)g,
      (__attribute__((address_space(3))) void*)l, 16, 0, 0);
}

// ---- inverse patch map: inv[bh][p] = selected index kk, or -1 ------------
__global__ __launch_bounds__(512)
void k_inv(const int* __restrict__ topk, int* __restrict__ inv){
  inv[blockIdx.x*NPATCH + topk[blockIdx.x*KSEL + threadIdx.x]] = threadIdx.x;
}

// ---- token build: dense layout-order read of x, write selected tokens ----
__global__ __launch_bounds__(256)
void k_tok(const float* __restrict__ x, const int* __restrict__ inv,
           u16* __restrict__ tok){
  __shared__ u16 tile[64][132];   // [d][pix]
  __shared__ int invs[32];
  const int tid = threadIdx.x;
  const int pr = blockIdx.x, bh = blockIdx.y;
  const int b = bh >> 3, h = bh & 7;
  if (tid < 32) invs[tid] = inv[bh*NPATCH + pr*32 + tid];
  const float* xb = x + ((size_t)(b*512 + h*64)*64 + 2*pr)*64;
  #pragma unroll
  for (int i = 0; i < 8; ++i){
    const int f = i*1024 + tid*4;
    const int d = f >> 7, y = (f >> 6) & 1, xx = f & 63;
    float4 v = *(const float4*)(xb + ((size_t)d*64 + y)*64 + xx);
    unsigned lo, hi;
    asm("v_cvt_pk_bf16_f32 %0, %1, %2" : "=v"(lo) : "v"(v.x), "v"(v.y));
    asm("v_cvt_pk_bf16_f32 %0, %1, %2" : "=v"(hi) : "v"(v.z), "v"(v.w));
    uint2 pk2; pk2.x = lo; pk2.y = hi;
    *(uint2*)&tile[d][y*64 + xx] = pk2;
  }
  __syncthreads();
  const int p = tid >> 3, j = tid & 7;
  const int kk = invs[p];
  if (kk >= 0){
    u16* dst = tok + ((size_t)bh*T_TOK + kk*4)*64;
    #pragma unroll
    for (int i = 0; i < 4; ++i){
      const int chunk = j*4 + i;
      const int quad = chunk >> 3, d16 = (chunk & 7)*8;
      const int pix = (quad >> 1)*64 + p*2 + (quad & 1);
      union { u16 s[8]; uint4 q; } un;
      #pragma unroll
      for (int k2 = 0; k2 < 8; ++k2) un.s[k2] = tile[d16 + k2][pix];
      *(uint4*)(dst + quad*64 + d16) = un.q;
    }
  }
}

// ---- QKV GEMM: tokens x W -> Qp, Kp, Vp (all frag-major, coalesced) ------
__global__ __launch_bounds__(256)
void k_qkv(const u16* __restrict__ tok, const float* __restrict__ w,
           const float* __restrict__ bias,
           u16* __restrict__ Qp, u16* __restrict__ Kp, u16* __restrict__ Vp){
  __shared__ u16 Wl[192][72];
  __shared__ float biasl[192];
  __shared__ u16 Tq[64][72];   // [q][d]
  __shared__ u16 Tk[64][72];   // [key][d]
  __shared__ u16 Tv[64][72];   // [d][key]  (transposed for b128 frag reads)
  const int tid = threadIdx.x;
  const int chunk = blockIdx.x;
  const int bh = blockIdx.y;
  for (int i2 = tid; i2 < 192*64; i2 += 256) Wl[i2 >> 6][i2 & 63] = f2bf(w[i2]);
  if (tid < 192) biasl[tid] = bias[tid];
  __syncthreads();

  const int lane = tid & 63, wv = tid >> 6;
  const int c = lane & 15, g = lane >> 4;
  const float QSC = 0.18033688f;   // 0.125 * log2(e)
  for (int tile = 0; tile < 4; ++tile){
    const int t0 = chunk*256 + tile*64;
    const int kt2 = t0 >> 6;
    const int trow = t0 + wv*16 + c;
    const u16* tr = tok + ((size_t)bh*T_TOK + trow)*64;
    const bf16x8 a0 = *(const bf16x8*)(tr + 8*g);
    const bf16x8 a1 = *(const bf16x8*)(tr + 32 + 8*g);
    const int lr = wv*16 + 4*g;           // local output row base (0..60)
    #pragma unroll
    for (int nf = 0; nf < 12; ++nf){
      const int e = nf*16 + c;
      const bf16x8 b0 = *(const bf16x8*)&Wl[e][8*g];
      const bf16x8 b1 = *(const bf16x8*)&Wl[e][32 + 8*g];
      f32x4 acc = {0.f, 0.f, 0.f, 0.f};
      acc = __builtin_amdgcn_mfma_f32_16x16x32_bf16(a0, b0, acc, 0, 0, 0);
      acc = __builtin_amdgcn_mfma_f32_16x16x32_bf16(a1, b1, acc, 0, 0, 0);
      const float bb = biasl[e];
      if (e < 64){
        #pragma unroll
        for (int r2 = 0; r2 < 4; ++r2) Tq[lr + r2][e] = f2bf((acc[r2] + bb)*QSC);
      } else if (e < 128){
        #pragma unroll
        for (int r2 = 0; r2 < 4; ++r2) Tk[lr + r2][e - 64] = f2bf(acc[r2] + bb);
      } else {
        // Tv[d][key]: 4 consecutive keys -> one 8B write
        unsigned u01 = (unsigned)f2bf(acc[0] + bb) | ((unsigned)f2bf(acc[1] + bb) << 16);
        unsigned u23 = (unsigned)f2bf(acc[2] + bb) | ((unsigned)f2bf(acc[3] + bb) << 16);
        uint2 pk2; pk2.x = u01; pk2.y = u23;
        *(uint2*)&Tv[e - 128][lr] = pk2;
      }
    }
    __syncthreads();
    // coalesced frag-major stores: thread -> two 16B slots per tensor
    #pragma unroll
    for (int c2 = 0; c2 < 2; ++c2){
      const int s  = tid*2 + c2;        // 0..511
      const int ls = s & 63, f = s >> 6;
      const int r31 = ls & 31, h2 = ls >> 5;
      // Q: f = g2*4 + kd
      {
        const int g2 = f >> 2, kd = f & 3;
        const bf16x8 v = *(const bf16x8*)&Tq[g2*32 + r31][kd*16 + h2*8];
        *(bf16x8*)(Qp + (size_t)bh*131072 + ((size_t)((t0 >> 5) + g2)*4 + kd)*512 + ls*8) = v;
      }
      // K: f = ds*2 + rh
      {
        const int ds = f >> 1, rh = f & 1;
        const bf16x8 v = *(const bf16x8*)&Tk[rh*32 + r31][ds*16 + h2*8];
        *(bf16x8*)(Kp + (((size_t)bh*32 + kt2)*8 + f)*512 + ls*8) = v;
      }
      // V: f = ks*2 + C
      {
        const int ks = f >> 1, C = f & 1;
        const bf16x8 v = *(const bf16x8*)&Tv[C*32 + r31][ks*16 + h2*8];
        *(bf16x8*)(Vp + (((size_t)bh*32 + kt2)*8 + f)*512 + ls*8) = v;
      }
    }
    __syncthreads();
  }
}

// ---- flash attention: 4 waves x 32 q-rows, phase-staggered blocks --------
// Frag-major K/V DMA'd to LDS (conflict-free reads). P via integer
// bf16-Schraudolph; row-sum via ones-MFMA (accS). Same-CU blocks (qt>>2
// distinct) start s_sleep-staggered so SM-VALU of one block fills the
// MFMA shadow of another (breaks the CU-wide phase convoy).
__global__ __launch_bounds__(256, 4)
void k_attn(const u16* __restrict__ Qp, const u16* __restrict__ Kp,
            const u16* __restrict__ Vp, float* __restrict__ OT){
  __shared__ u16 KVl[2][8192];   // per buf: 8 K frags [64][8] + 8 V frags
  const int tid = threadIdx.x;
  const int bh = blockIdx.x, qt = blockIdx.y;   // bh-major: qt blocks share one XCD's L2
  const int l = tid & 63, w = tid >> 6;
  const int h = l >> 5, c31 = l & 31;
  const int qbase = qt*128 + w*32;

  // phase stagger: same-CU blocks have qt = q, q+4, q+8, q+12
  {
    const int ph = (qt >> 2) & 3;
    if (ph == 1)      asm volatile("s_sleep 6");
    else if (ph == 2) asm volatile("s_sleep 12");
    else if (ph == 3) asm volatile("s_sleep 18");
  }

  // Q fragments: frag-major, coalesced 16B/lane
  bf16x8 qf[4];
  {
    const u16* qpb = Qp + (size_t)bh*131072 + ((size_t)(qt*4 + w)*4)*512 + l*8;
    #pragma unroll
    for (int kd = 0; kd < 4; ++kd) qf[kd] = *(const bf16x8*)(qpb + kd*512);
  }

  bf16x8 ones;
  #pragma unroll
  for (int j = 0; j < 8; ++j) ones[j] = (short)0x3F80;

  f32x16 Z;
  #pragma unroll
  for (int r = 0; r < 16; ++r) Z[r] = 0.f;
  f32x16 accO0 = Z, accO1 = Z, accS = Z;

  const u16* gKt = Kp + (size_t)bh*131072;   // 32 tiles x 4096 u16
  const u16* gVt = Vp + (size_t)bh*131072;

  // prologue: DMA tile 0 into buffer 0
  {
    u16* ld = &KVl[0][0] + tid*8;
    gload16(gKt + tid*8,        ld);
    gload16(gKt + 2048 + tid*8, ld + 2048);
    gload16(gVt + tid*8,        ld + 4096);
    gload16(gVt + 2048 + tid*8, ld + 6144);
  }
  __syncthreads();

  int cur = 0;
  for (int kt = 0; kt < 32; ++kt){
    if (kt < 31){   // DMA next tile into the other buffer (drained by end barrier)
      const u16* sk = gKt + (kt + 1)*4096 + tid*8;
      const u16* sv = gVt + (kt + 1)*4096 + tid*8;
      u16* ld = &KVl[cur ^ 1][0] + tid*8;
      gload16(sk,        ld);
      gload16(sk + 2048, ld + 2048);
      gload16(sv,        ld + 4096);
      gload16(sv + 2048, ld + 6144);
    }

    const u16* kb = &KVl[cur][l*8];   // frag f at u16 offset f*512
    const u16* vb = kb + 4096;

    // ---- QK: s0 chain (keys 0..31), then s1 chain (keys 32..63) ----
    f32x16 s0, s1;
    __builtin_amdgcn_s_setprio(1);
    s0 = __builtin_amdgcn_mfma_f32_32x32x16_bf16(*(const bf16x8*)(kb),        qf[0], Z,  0, 0, 0);
    s0 = __builtin_amdgcn_mfma_f32_32x32x16_bf16(*(const bf16x8*)(kb + 1024), qf[1], s0, 0, 0, 0);
    s0 = __builtin_amdgcn_mfma_f32_32x32x16_bf16(*(const bf16x8*)(kb + 2048), qf[2], s0, 0, 0, 0);
    s0 = __builtin_amdgcn_mfma_f32_32x32x16_bf16(*(const bf16x8*)(kb + 3072), qf[3], s0, 0, 0, 0);
    s1 = __builtin_amdgcn_mfma_f32_32x32x16_bf16(*(const bf16x8*)(kb + 512),  qf[0], Z,  0, 0, 0);
    s1 = __builtin_amdgcn_mfma_f32_32x32x16_bf16(*(const bf16x8*)(kb + 1536), qf[1], s1, 0, 0, 0);
    s1 = __builtin_amdgcn_mfma_f32_32x32x16_bf16(*(const bf16x8*)(kb + 2560), qf[2], s1, 0, 0, 0);
    s1 = __builtin_amdgcn_mfma_f32_32x32x16_bf16(*(const bf16x8*)(kb + 3584), qf[3], s1, 0, 0, 0);
    __builtin_amdgcn_s_setprio(0);

    // ---- SM(s0): bf16-Schraudolph exp2 patterns -> paf0, paf1 ----
    unsigned pk0[8];
    #pragma unroll
    for (int i = 0; i < 8; ++i){
      const int lo = (int)fmaf(s0[2*i],   128.f, EMAGIC);
      const int hi = (int)fmaf(s0[2*i+1], 128.f, EMAGIC);
      pk0[i] = (unsigned)(lo | (hi << 16));
    }
    bf16x8 paf0, paf1;
    {
      unsigned a0 = pk0[0], b0 = pk0[2], a1 = pk0[1], b1 = pk0[3];
      asm("v_permlane32_swap_b32 %0, %1" : "+v"(a0), "+v"(b0));
      asm("v_permlane32_swap_b32 %0, %1" : "+v"(a1), "+v"(b1));
      union { unsigned u[4]; bf16x8 v; } un;
      un.u[0] = a0; un.u[1] = a1; un.u[2] = b0; un.u[3] = b1;
      paf0 = un.v;
      unsigned c0 = pk0[4], d0 = pk0[6], c1 = pk0[5], d1 = pk0[7];
      asm("v_permlane32_swap_b32 %0, %1" : "+v"(c0), "+v"(d0));
      asm("v_permlane32_swap_b32 %0, %1" : "+v"(c1), "+v"(d1));
      union { unsigned u[4]; bf16x8 v; } un2;
      un2.u[0] = c0; un2.u[1] = c1; un2.u[2] = d0; un2.u[3] = d1;
      paf1 = un2.v;
    }

    // ---- PV ks=0,1 + row-sum MFMAs ----
    __builtin_amdgcn_s_setprio(1);
    accO0 = __builtin_amdgcn_mfma_f32_32x32x16_bf16(paf0, *(const bf16x8*)(vb),        accO0, 0, 0, 0);
    accO1 = __builtin_amdgcn_mfma_f32_32x32x16_bf16(paf0, *(const bf16x8*)(vb + 512),  accO1, 0, 0, 0);
    accS  = __builtin_amdgcn_mfma_f32_32x32x16_bf16(paf0, ones,                        accS,  0, 0, 0);
    accO0 = __builtin_amdgcn_mfma_f32_32x32x16_bf16(paf1, *(const bf16x8*)(vb + 1024), accO0, 0, 0, 0);
    accO1 = __builtin_amdgcn_mfma_f32_32x32x16_bf16(paf1, *(const bf16x8*)(vb + 1536), accO1, 0, 0, 0);
    accS  = __builtin_amdgcn_mfma_f32_32x32x16_bf16(paf1, ones,                        accS,  0, 0, 0);
    __builtin_amdgcn_s_setprio(0);

    // ---- SM(s1) ----
    unsigned pk1[8];
    #pragma unroll
    for (int i = 0; i < 8; ++i){
      const int lo = (int)fmaf(s1[2*i],   128.f, EMAGIC);
      const int hi = (int)fmaf(s1[2*i+1], 128.f, EMAGIC);
      pk1[i] = (unsigned)(lo | (hi << 16));
    }
    bf16x8 paf2, paf3;
    {
      unsigned a0 = pk1[0], b0 = pk1[2], a1 = pk1[1], b1 = pk1[3];
      asm("v_permlane32_swap_b32 %0, %1" : "+v"(a0), "+v"(b0));
      asm("v_permlane32_swap_b32 %0, %1" : "+v"(a1), "+v"(b1));
      union { unsigned u[4]; bf16x8 v; } un;
      un.u[0] = a0; un.u[1] = a1; un.u[2] = b0; un.u[3] = b1;
      paf2 = un.v;
      unsigned c0 = pk1[4], d0 = pk1[6], c1 = pk1[5], d1 = pk1[7];
      asm("v_permlane32_swap_b32 %0, %1" : "+v"(c0), "+v"(d0));
      asm("v_permlane32_swap_b32 %0, %1" : "+v"(c1), "+v"(d1));
      union { unsigned u[4]; bf16x8 v; } un2;
      un2.u[0] = c0; un2.u[1] = c1; un2.u[2] = d0; un2.u[3] = d1;
      paf3 = un2.v;
    }

    // ---- PV ks=2,3 + row-sum MFMAs ----
    __builtin_amdgcn_s_setprio(1);
    accO0 = __builtin_amdgcn_mfma_f32_32x32x16_bf16(paf2, *(const bf16x8*)(vb + 2048), accO0, 0, 0, 0);
    accO1 = __builtin_amdgcn_mfma_f32_32x32x16_bf16(paf2, *(const bf16x8*)(vb + 2560), accO1, 0, 0, 0);
    accS  = __builtin_amdgcn_mfma_f32_32x32x16_bf16(paf2, ones,                        accS,  0, 0, 0);
    accO0 = __builtin_amdgcn_mfma_f32_32x32x16_bf16(paf3, *(const bf16x8*)(vb + 3072), accO0, 0, 0, 0);
    accO1 = __builtin_amdgcn_mfma_f32_32x32x16_bf16(paf3, *(const bf16x8*)(vb + 3584), accO1, 0, 0, 0);
    accS  = __builtin_amdgcn_mfma_f32_32x32x16_bf16(paf3, ones,                        accS,  0, 0, 0);
    __builtin_amdgcn_s_setprio(0);

    __syncthreads();   // drains next-tile DMA + buffer-swap safety
    cur ^= 1;
  }

  // ---- epilogue: normalize via accS (rows aligned with accO), store ------
  #pragma unroll
  for (int r = 0; r < 16; ++r){
    const int qr = (r & 3) + 8*(r >> 2) + 4*h;
    const float sa = __builtin_amdgcn_rcpf(accS[r]);
    float* dst = OT + ((size_t)bh*T_TOK + qbase + qr)*64;
    dst[c31]      = accO0[r]*sa;
    dst[32 + c31] = accO1[r]*sa;
  }
}

// ---- emit: both-sides-coalesced via LDS transpose ------------------------
__global__ __launch_bounds__(256)
void k_emit(const float* __restrict__ OT, const int* __restrict__ inv,
            float* __restrict__ out){
  __shared__ float obuf[128][68];   // [pix = y*64+x][d], pad 4
  __shared__ int invs[32];
  const int tid = threadIdx.x;
  const int pr = blockIdx.x, bh = blockIdx.y;
  const int b = bh >> 3, h = bh & 7;
  if (tid < 32) invs[tid] = inv[bh*NPATCH + pr*32 + tid];
  __syncthreads();
  const int g = tid >> 3, j = tid & 7;
  const int kk = invs[g];
  const float* tbase = OT + ((size_t)bh*T_TOK + 4*kk)*64 + j*8;
  #pragma unroll
  for (int quad = 0; quad < 4; ++quad){
    float4 v0 = {0.f,0.f,0.f,0.f}, v1 = {0.f,0.f,0.f,0.f};
    if (kk >= 0){
      v0 = *(const float4*)(tbase + quad*64);
      v1 = *(const float4*)(tbase + quad*64 + 4);
    }
    const int pix = (quad >> 1)*64 + g*2 + (quad & 1);
    *(float4*)&obuf[pix][j*8]     = v0;
    *(float4*)&obuf[pix][j*8 + 4] = v1;
  }
  __syncthreads();
  float* ob = out + ((size_t)(b*512 + h*64)*64 + 2*pr)*64;
  #pragma unroll
  for (int it = 0; it < 8; ++it){
    const int rid = it*16 + (tid >> 4);      // d*2 + y
    const int d = rid >> 1, y = rid & 1;
    const int x0 = (tid & 15)*4;
    float4 o;
    o.x = obuf[y*64 + x0 + 0][d];
    o.y = obuf[y*64 + x0 + 1][d];
    o.z = obuf[y*64 + x0 + 2][d];
    o.w = obuf[y*64 + x0 + 3][d];
    *(float4*)(ob + ((size_t)d*64 + y)*64 + x0) = o;
  }
}

extern "C" void kernel_launch(void* const* d_in, const int* in_sizes, int n_in,
                              void* d_out, int out_size, void* d_ws, size_t ws_size,
                              hipStream_t stream){
  const float* x    = (const float*)d_in[0];
  const int*   topk = (const int*)  d_in[1];
  const float* w    = (const float*)d_in[2];
  const float* bias = (const float*)d_in[3];
  float* out = (float*)d_out;
  char* ws = (char*)d_ws;

  u16*   Qp  = (u16*)  (ws + WS_Q);
  u16*   Kp  = (u16*)  (ws + WS_K);
  u16*   Vp  = (u16*)  (ws + WS_VT);
  float* OT  = (float*)(ws + WS_OT);
  u16*   tok = (u16*)  (ws + WS_OT);   // aliases OT; dead before k_attn writes
  int*   inv = (int*)  (ws + WS_INV);

  hipMemsetAsync(inv, 0xFF, BH_N*NPATCH*sizeof(int), stream);
  k_inv <<<BH_N, 512, 0, stream>>>(topk, inv);
  k_tok <<<dim3(32, BH_N), 256, 0, stream>>>(x, inv, tok);
  k_qkv <<<dim3(8, BH_N), 256, 0, stream>>>(tok, w, bias, Qp, Kp, Vp);
  k_attn<<<dim3(BH_N, 16), 256, 0, stream>>>(Qp, Kp, Vp, OT);
  k_emit<<<dim3(32, BH_N), 256, 0, stream>>>(OT, inv, out);
}